// Round 11
// baseline (118.825 us; speedup 1.0000x reference)
//
#include <hip/hip_runtime.h>

#define B_ 4
#define S_ 512
#define T_ 512
#define D_ 256
#define NSRC (B_ * S_)            // 2048 source rows (= target rows)
#define K2F 2.8853900817779268f   // 2*log2(e): exp2(x*K2F) = e^(2x)

typedef __attribute__((ext_vector_type(8))) short short8;   // 8 bf16
typedef __attribute__((ext_vector_type(4))) float f32x4;
typedef __attribute__((ext_vector_type(2))) float f32x2;

__device__ __forceinline__ unsigned short f2bf(float f) {
    union { float f; unsigned u; } v; v.f = f;
    unsigned r = v.u + 0x7FFF + ((v.u >> 16) & 1);   // RNE
    return (unsigned short)(r >> 16);
}

// ---------------------------------------------------------------------------
// K1: prep (validated R3). blocks 0..1023: cast [src;tgt] -> abf bf16.
//     blocks 1024..1055: W -> WT bf16 via LDS 64x64 tile transpose.
//     blocks 1056..1567: prob = softmax(target @ W_prob + b_prob).
// ---------------------------------------------------------------------------
__global__ __launch_bounds__(256) void prep_kernel(
    const float* __restrict__ src, const float* __restrict__ tgt,
    const float* __restrict__ Wsrc, const float* __restrict__ Wtgt,
    const float* __restrict__ Wp, const float* __restrict__ bp,
    unsigned short* __restrict__ abf, unsigned short* __restrict__ wtb,
    float* __restrict__ out)
{
    __shared__ float tl[64 * 65];
    const int blk = blockIdx.x, tid = threadIdx.x;

    if (blk < 1024) {
        int i4 = blk * 256 + tid;
        const int half = NSRC * D_ / 4;
        const float4* in = (i4 < half) ? (const float4*)src : (const float4*)tgt;
        int j = (i4 < half) ? i4 : i4 - half;
        float4 v = in[j];
        ushort4 o;
        o.x = f2bf(v.x); o.y = f2bf(v.y); o.z = f2bf(v.z); o.w = f2bf(v.w);
        *(ushort4*)&abf[i4 * 4] = o;
    } else if (blk < 1056) {
        int wb = blk - 1024;
        int e = wb >> 4, ti = wb & 15, tr = ti >> 2, tc = ti & 3;
        int r0 = tr * 64, c0 = tc * 64;
        const float* W = e ? Wtgt : Wsrc;
        #pragma unroll
        for (int it = 0; it < 4; it++) {
            int rr = (tid >> 4) + it * 16;
            int cc = (tid & 15) * 4;
            float4 v = *(const float4*)&W[(r0 + rr) * D_ + c0 + cc];
            tl[(cc + 0) * 65 + rr] = v.x;
            tl[(cc + 1) * 65 + rr] = v.y;
            tl[(cc + 2) * 65 + rr] = v.z;
            tl[(cc + 3) * 65 + rr] = v.w;
        }
        __syncthreads();
        #pragma unroll
        for (int it = 0; it < 2; it++) {
            int jj = (tid >> 3) + it * 32;
            int kk = (tid & 7) * 8;
            ushort4 lo, hi;
            lo.x = f2bf(tl[jj * 65 + kk + 0]); lo.y = f2bf(tl[jj * 65 + kk + 1]);
            lo.z = f2bf(tl[jj * 65 + kk + 2]); lo.w = f2bf(tl[jj * 65 + kk + 3]);
            hi.x = f2bf(tl[jj * 65 + kk + 4]); hi.y = f2bf(tl[jj * 65 + kk + 5]);
            hi.z = f2bf(tl[jj * 65 + kk + 6]); hi.w = f2bf(tl[jj * 65 + kk + 7]);
            int idx = (e * 256 + c0 + jj) * D_ + r0 + kk;
            *(ushort4*)&wtb[idx] = lo;
            *(ushort4*)&wtb[idx + 4] = hi;
        }
    } else {
        int row  = (blk - 1056) * 4 + (tid >> 6);
        int lane = tid & 63;
        float p0 = 0.f, p1 = 0.f;
        #pragma unroll
        for (int i = 0; i < 4; i++) {
            int d = lane + i * 64;
            float v = tgt[row * D_ + d];
            float2 w = *(const float2*)&Wp[d * 2];
            p0 = fmaf(v, w.x, p0);
            p1 = fmaf(v, w.y, p1);
        }
        #pragma unroll
        for (int off = 32; off > 0; off >>= 1) {
            p0 += __shfl_down(p0, off, 64);
            p1 += __shfl_down(p1, off, 64);
        }
        if (lane == 0) {
            const float L2E = 1.4426950408889634f;
            float l0 = p0 + bp[0], l1 = p1 + bp[1];
            float e10 = __builtin_amdgcn_exp2f((l1 - l0) * L2E);
            float e01 = __builtin_amdgcn_exp2f((l0 - l1) * L2E);
            out[B_ * T_ * S_ + row * 2 + 0] = __builtin_amdgcn_rcpf(1.f + e10);
            out[B_ * T_ * S_ + row * 2 + 1] = __builtin_amdgcn_rcpf(1.f + e01);
        }
    }
}

// ---------------------------------------------------------------------------
// K2: linT — R2-validated MFMA lin kernel, TRANSPOSED store:
// yaT/ycT[d][row] = exp2((A@W + b)*K2F). 512 blocks x 256 thr; wave = 16 rows
// x 32 cols. D-frag rows quad*4+i are contiguous -> one float4 store per frag.
// ---------------------------------------------------------------------------
__global__ __launch_bounds__(256) void linT_kernel(
    const unsigned short* __restrict__ abf, const unsigned short* __restrict__ wtb,
    const float* __restrict__ bsrc, const float* __restrict__ btgt,
    float* __restrict__ yaT, float* __restrict__ ycT)
{
    int wid  = blockIdx.x * 4 + (threadIdx.x >> 6);   // 0..2047
    int lane = threadIdx.x & 63;
    int rg = wid >> 3;                                // 0..255 row-group
    int cg = wid & 7;                                 // 0..7 col-group (32 cols)
    int e  = rg >> 7;                                 // 0 src, 1 tgt
    int r0 = rg * 16;                                 // row in abf (0..4095)
    int n = lane & 15, quad = lane >> 4;

    const float* bias = e ? btgt : bsrc;
    float* outT = e ? ycT : yaT;
    int orow0 = r0 - e * NSRC;

    int ct0 = cg * 2, ct1 = cg * 2 + 1;
    f32x4 acc0 = {0.f, 0.f, 0.f, 0.f};
    f32x4 acc1 = {0.f, 0.f, 0.f, 0.f};

    const unsigned short* aP  = &abf[(r0 + n) * D_ + quad * 8];
    const unsigned short* b0P = &wtb[(e * 256 + ct0 * 16 + n) * D_ + quad * 8];
    const unsigned short* b1P = &wtb[(e * 256 + ct1 * 16 + n) * D_ + quad * 8];

    #pragma unroll
    for (int ks = 0; ks < 8; ks++) {
        short8 a  = *(const short8*)&aP[ks * 32];
        short8 b0 = *(const short8*)&b0P[ks * 32];
        short8 b1 = *(const short8*)&b1P[ks * 32];
        acc0 = __builtin_amdgcn_mfma_f32_16x16x32_bf16(a, b0, acc0, 0, 0, 0);
        acc1 = __builtin_amdgcn_mfma_f32_16x16x32_bf16(a, b1, acc1, 0, 0, 0);
    }

    float b0v = bias[ct0 * 16 + n];
    float b1v = bias[ct1 * 16 + n];
    float4 o0, o1;
    o0.x = __builtin_amdgcn_exp2f((acc0[0] + b0v) * K2F);
    o0.y = __builtin_amdgcn_exp2f((acc0[1] + b0v) * K2F);
    o0.z = __builtin_amdgcn_exp2f((acc0[2] + b0v) * K2F);
    o0.w = __builtin_amdgcn_exp2f((acc0[3] + b0v) * K2F);
    o1.x = __builtin_amdgcn_exp2f((acc1[0] + b1v) * K2F);
    o1.y = __builtin_amdgcn_exp2f((acc1[1] + b1v) * K2F);
    o1.z = __builtin_amdgcn_exp2f((acc1[2] + b1v) * K2F);
    o1.w = __builtin_amdgcn_exp2f((acc1[3] + b1v) * K2F);
    *(float4*)&outT[(ct0 * 16 + n) * NSRC + orow0 + quad * 4] = o0;
    *(float4*)&outT[(ct1 * 16 + n) * NSRC + orow0 + quad * 4] = o1;
}

// ---------------------------------------------------------------------------
// K3: genp — all-worker, 4-way k-split. Grid (8,8,4)=256 blocks, 1024 thr =
// 16 waves = 4/SIMD. Per 64-d chunk: coalesced conflict-free row staging
// (1 b32 row per wave-instr) -> barrier -> each set (4 waves) grinds its 16-d
// slice: 8 kp of 4x4 tile, d-pair rcp folding, packed f32x2 math, NO barriers.
// LDS-tree reduction of 4 partials at the end (padded slots, conflict-free).
// genP = C0 - 2 * sum_d w_d / (1 + ys*yt),  C0 = sum w + b_res.
// ---------------------------------------------------------------------------
#define GSTR 68
__global__ __launch_bounds__(1024, 4) void genp_kernel(
    const float* __restrict__ yaT, const float* __restrict__ ycT,
    const float* __restrict__ Wres, const float* __restrict__ bres,
    float* __restrict__ out)
{
    __shared__ float lbuf[2 * 64 * GSTR];   // 34.8 KB: ls | lt ; reused for reduce
    float* ls = lbuf;
    float* lt = lbuf + 64 * GSTR;
    __shared__ float c0s;

    const int tid = threadIdx.x;
    const int lane = tid & 63, w = tid >> 6;   // 16 waves
    const int s0 = blockIdx.x * 64;
    const int t0 = blockIdx.y * 64;
    const int b  = blockIdx.z;
    const int sg = b * S_ + s0;
    const int tg = b * T_ + t0;

    if (w == 0) {
        float s = Wres[lane] + Wres[lane + 64] + Wres[lane + 128] + Wres[lane + 192];
        #pragma unroll
        for (int off = 32; off > 0; off >>= 1) s += __shfl_xor(s, off, 64);
        if (lane == 0) c0s = s + bres[0];
    }

    const int q = w >> 2;                       // k-split set 0..3
    const int m = lane & 15;                    // s = s0 + 4m..4m+3
    const int g = (w & 3) * 4 + (lane >> 4);    // t = t0 + 4g..4g+3
    const int dbase = q * 16;                   // set's dloc slice

    f32x2 acc[4][2];                            // [i (t)][jp (s-pair)]
    #pragma unroll
    for (int i = 0; i < 4; i++) {
        acc[i][0] = (f32x2){0.f, 0.f};
        acc[i][1] = (f32x2){0.f, 0.f};
    }

    for (int c = 0; c < 4; c++) {
        __syncthreads();   // previous chunk's readers done
        // stage 128 rows: ls[r][s] / lt[r][t], 1 b32 row per wave-instr
        #pragma unroll
        for (int j = 0; j < 8; j++) {
            int r = w * 8 + j;
            if (r < 64) ls[r * GSTR + lane] = yaT[(c * 64 + r) * NSRC + sg + lane];
            else        lt[(r - 64) * GSTR + lane] = ycT[(c * 64 + r - 64) * NSRC + tg + lane];
        }
        __syncthreads();

        const float* wp = &Wres[c * 64 + dbase];
        const f32x2 one2 = {1.f, 1.f};
        #pragma unroll
        for (int kp = 0; kp < 8; kp++) {
            const int d0 = dbase + 2 * kp, d1 = d0 + 1;
            float4 av0 = *(const float4*)&ls[d0 * GSTR + 4 * m];
            float4 av1 = *(const float4*)&ls[d1 * GSTR + 4 * m];
            float4 cv0 = *(const float4*)&lt[d0 * GSTR + 4 * g];
            float4 cv1 = *(const float4*)&lt[d1 * GSTR + 4 * g];
            const float w0 = wp[2 * kp], w1 = wp[2 * kp + 1];   // uniform s_load
            const f32x2 w0v = {w0, w0}, w1v = {w1, w1};
            f32x2 a0p[2] = {{av0.x, av0.y}, {av0.z, av0.w}};
            f32x2 a1p[2] = {{av1.x, av1.y}, {av1.z, av1.w}};
            const float cc0[4] = {cv0.x, cv0.y, cv0.z, cv0.w};
            const float cc1[4] = {cv1.x, cv1.y, cv1.z, cv1.w};
            #pragma unroll
            for (int i = 0; i < 4; i++) {
                const f32x2 c0v = {cc0[i], cc0[i]};
                const f32x2 c1v = {cc1[i], cc1[i]};
                #pragma unroll
                for (int jp = 0; jp < 2; jp++) {
                    f32x2 dd0 = a0p[jp] * c0v + one2;    // 1 + y0
                    f32x2 dd1 = a1p[jp] * c1v + one2;    // 1 + y1
                    f32x2 den = dd0 * dd1;
                    f32x2 tnu = dd0 * w1v;
                    f32x2 num = dd1 * w0v + tnu;         // w0*dd1 + w1*dd0
                    f32x2 r;
                    r.x = __builtin_amdgcn_rcpf(den.x);
                    r.y = __builtin_amdgcn_rcpf(den.y);
                    acc[i][jp] = num * r + acc[i][jp];
                }
            }
        }
    }

    // ---- reduction of 4 set-partials: q1->q0, q3->q2, then q2->q0 ----
    __syncthreads();
    const int slot = ((w & 3) * 64 + lane) * 17;         // = (g*16+m)*17
    const int slotH = ((q >> 1) * 256 + (w & 3) * 64 + lane) * 17;
    if (q == 1 || q == 3) {
        #pragma unroll
        for (int i = 0; i < 4; i++) {
            float4 p = {acc[i][0].x, acc[i][0].y, acc[i][1].x, acc[i][1].y};
            *(float4*)&lbuf[slotH + 4 * i] = p;
        }
    }
    __syncthreads();
    if (q == 0 || q == 2) {
        #pragma unroll
        for (int i = 0; i < 4; i++) {
            float4 p = *(const float4*)&lbuf[slotH + 4 * i];
            acc[i][0].x += p.x; acc[i][0].y += p.y;
            acc[i][1].x += p.z; acc[i][1].y += p.w;
        }
    }
    __syncthreads();
    if (q == 2) {
        #pragma unroll
        for (int i = 0; i < 4; i++) {
            float4 p = {acc[i][0].x, acc[i][0].y, acc[i][1].x, acc[i][1].y};
            *(float4*)&lbuf[slot + 4 * i] = p;
        }
    }
    __syncthreads();
    if (q == 0) {
        const float C0 = c0s;
        #pragma unroll
        for (int i = 0; i < 4; i++) {
            float4 p = *(const float4*)&lbuf[slot + 4 * i];
            float4 o;
            o.x = C0 - 2.f * (acc[i][0].x + p.x);
            o.y = C0 - 2.f * (acc[i][0].y + p.y);
            o.z = C0 - 2.f * (acc[i][1].x + p.z);
            o.w = C0 - 2.f * (acc[i][1].y + p.w);
            *(float4*)&out[(b * T_ + t0 + 4 * g + i) * S_ + s0 + 4 * m] = o;
        }
    }
}

extern "C" void kernel_launch(void* const* d_in, const int* in_sizes, int n_in,
                              void* d_out, int out_size, void* d_ws, size_t ws_size,
                              hipStream_t stream) {
    const float* source = (const float*)d_in[0];
    const float* target = (const float*)d_in[1];
    const float* W_src  = (const float*)d_in[2];
    const float* b_src  = (const float*)d_in[3];
    const float* W_tgt  = (const float*)d_in[4];
    const float* b_tgt  = (const float*)d_in[5];
    const float* W_res  = (const float*)d_in[6];
    const float* b_res  = (const float*)d_in[7];
    const float* W_prob = (const float*)d_in[8];
    const float* b_prob = (const float*)d_in[9];
    float* out = (float*)d_out;

    unsigned short* abf = (unsigned short*)d_ws;        // 4096*256 bf16 = 2 MB
    unsigned short* wtb = abf + 2 * NSRC * D_;          // 2*256*256 bf16 = 256 KB
    float* yaT = (float*)(wtb + 2 * D_ * D_);           // [256][2048] = 2 MB
    float* ycT = yaT + D_ * NSRC;                       // [256][2048] = 2 MB

    prep_kernel<<<1568, 256, 0, stream>>>(source, target, W_src, W_tgt,
                                          W_prob, b_prob, abf, wtb, out);
    linT_kernel<<<512, 256, 0, stream>>>(abf, wtb, b_src, b_tgt, yaT, ycT);
    genp_kernel<<<dim3(8, 8, 4), 1024, 0, stream>>>(yaT, ycT, W_res, b_res, out);
}

// Round 12
// 116.573 us; speedup vs baseline: 1.0193x; 1.0193x over previous
//
#include <hip/hip_runtime.h>

#define B_ 4
#define S_ 512
#define T_ 512
#define D_ 256
#define NSRC (B_ * S_)            // 2048 source rows (= target rows)
#define K2F 2.8853900817779268f   // 2*log2(e): exp2(x*K2F) = e^(2x)

typedef __attribute__((ext_vector_type(8))) short short8;   // 8 bf16
typedef __attribute__((ext_vector_type(4))) float f32x4;
typedef __attribute__((ext_vector_type(2))) float f32x2;

__device__ __forceinline__ unsigned short f2bf(float f) {
    union { float f; unsigned u; } v; v.f = f;
    unsigned r = v.u + 0x7FFF + ((v.u >> 16) & 1);   // RNE
    return (unsigned short)(r >> 16);
}

// ---------------------------------------------------------------------------
// K1: prep (validated R3). blocks 0..1023: cast [src;tgt] -> abf bf16.
//     blocks 1024..1055: W -> WT bf16 via LDS 64x64 tile transpose.
//     blocks 1056..1567: prob = softmax(target @ W_prob + b_prob).
// ---------------------------------------------------------------------------
__global__ __launch_bounds__(256) void prep_kernel(
    const float* __restrict__ src, const float* __restrict__ tgt,
    const float* __restrict__ Wsrc, const float* __restrict__ Wtgt,
    const float* __restrict__ Wp, const float* __restrict__ bp,
    unsigned short* __restrict__ abf, unsigned short* __restrict__ wtb,
    float* __restrict__ out)
{
    __shared__ float tl[64 * 65];
    const int blk = blockIdx.x, tid = threadIdx.x;

    if (blk < 1024) {
        int i4 = blk * 256 + tid;
        const int half = NSRC * D_ / 4;
        const float4* in = (i4 < half) ? (const float4*)src : (const float4*)tgt;
        int j = (i4 < half) ? i4 : i4 - half;
        float4 v = in[j];
        ushort4 o;
        o.x = f2bf(v.x); o.y = f2bf(v.y); o.z = f2bf(v.z); o.w = f2bf(v.w);
        *(ushort4*)&abf[i4 * 4] = o;
    } else if (blk < 1056) {
        int wb = blk - 1024;
        int e = wb >> 4, ti = wb & 15, tr = ti >> 2, tc = ti & 3;
        int r0 = tr * 64, c0 = tc * 64;
        const float* W = e ? Wtgt : Wsrc;
        #pragma unroll
        for (int it = 0; it < 4; it++) {
            int rr = (tid >> 4) + it * 16;
            int cc = (tid & 15) * 4;
            float4 v = *(const float4*)&W[(r0 + rr) * D_ + c0 + cc];
            tl[(cc + 0) * 65 + rr] = v.x;
            tl[(cc + 1) * 65 + rr] = v.y;
            tl[(cc + 2) * 65 + rr] = v.z;
            tl[(cc + 3) * 65 + rr] = v.w;
        }
        __syncthreads();
        #pragma unroll
        for (int it = 0; it < 2; it++) {
            int jj = (tid >> 3) + it * 32;
            int kk = (tid & 7) * 8;
            ushort4 lo, hi;
            lo.x = f2bf(tl[jj * 65 + kk + 0]); lo.y = f2bf(tl[jj * 65 + kk + 1]);
            lo.z = f2bf(tl[jj * 65 + kk + 2]); lo.w = f2bf(tl[jj * 65 + kk + 3]);
            hi.x = f2bf(tl[jj * 65 + kk + 4]); hi.y = f2bf(tl[jj * 65 + kk + 5]);
            hi.z = f2bf(tl[jj * 65 + kk + 6]); hi.w = f2bf(tl[jj * 65 + kk + 7]);
            int idx = (e * 256 + c0 + jj) * D_ + r0 + kk;
            *(ushort4*)&wtb[idx] = lo;
            *(ushort4*)&wtb[idx + 4] = hi;
        }
    } else {
        int row  = (blk - 1056) * 4 + (tid >> 6);
        int lane = tid & 63;
        float p0 = 0.f, p1 = 0.f;
        #pragma unroll
        for (int i = 0; i < 4; i++) {
            int d = lane + i * 64;
            float v = tgt[row * D_ + d];
            float2 w = *(const float2*)&Wp[d * 2];
            p0 = fmaf(v, w.x, p0);
            p1 = fmaf(v, w.y, p1);
        }
        #pragma unroll
        for (int off = 32; off > 0; off >>= 1) {
            p0 += __shfl_down(p0, off, 64);
            p1 += __shfl_down(p1, off, 64);
        }
        if (lane == 0) {
            const float L2E = 1.4426950408889634f;
            float l0 = p0 + bp[0], l1 = p1 + bp[1];
            float e10 = __builtin_amdgcn_exp2f((l1 - l0) * L2E);
            float e01 = __builtin_amdgcn_exp2f((l0 - l1) * L2E);
            out[B_ * T_ * S_ + row * 2 + 0] = __builtin_amdgcn_rcpf(1.f + e10);
            out[B_ * T_ * S_ + row * 2 + 1] = __builtin_amdgcn_rcpf(1.f + e01);
        }
    }
}

// ---------------------------------------------------------------------------
// K2: linT v2 — swapped-operand MFMA so the transposed store is coalesced.
// D[m][n] = sum_k WT[d0+m][k] * abf[R0+16f+n][k]  (A-frag = WT rows resident,
// B-frag = abf rows streamed; both use the validated per-lane b128 pattern).
// D-layout: row(quad*4+i) = d-offset, col(n) = row-offset -> store writes 16
// consecutive floats per quad group = aligned 64-B segments (vs 16-B scatter
// in R11). Wave = 16 d x 64 rows; 1024 waves = 256 blocks.
// yaT/ycT[d][row] = exp2((A@W + b)*K2F).
// ---------------------------------------------------------------------------
__global__ __launch_bounds__(256) void linT_kernel(
    const unsigned short* __restrict__ abf, const unsigned short* __restrict__ wtb,
    const float* __restrict__ bsrc, const float* __restrict__ btgt,
    float* __restrict__ yaT, float* __restrict__ ycT)
{
    const int W    = blockIdx.x * 4 + (threadIdx.x >> 6);   // 0..1023
    const int lane = threadIdx.x & 63;
    const int rgrp = W >> 4;             // 0..63: 64-row group
    const int dg   = W & 15;             // 0..15: 16-d group
    const int e    = rgrp >> 5;          // 0 src, 1 tgt
    const int R0   = rgrp * 64;          // abf row base (0..4032)
    const int orow0 = R0 - e * NSRC;     // row base within its matrix
    const int d0   = dg * 16;
    const int n = lane & 15, quad = lane >> 4;

    const float* bias = e ? btgt : bsrc;
    float* outT = e ? ycT : yaT;

    // A-frag: WT rows d0+n (resident, full K)
    const unsigned short* aP = &wtb[(e * 256 + d0 + n) * D_ + quad * 8];
    short8 af[8];
    #pragma unroll
    for (int ks = 0; ks < 8; ks++) af[ks] = *(const short8*)&aP[ks * 32];

    const float4 vb = *(const float4*)&bias[d0 + quad * 4];

    #pragma unroll
    for (int f = 0; f < 4; f++) {
        const unsigned short* bP = &abf[(R0 + 16 * f + n) * D_ + quad * 8];
        f32x4 acc = {0.f, 0.f, 0.f, 0.f};
        #pragma unroll
        for (int ks = 0; ks < 8; ks++) {
            short8 bf = *(const short8*)&bP[ks * 32];
            acc = __builtin_amdgcn_mfma_f32_16x16x32_bf16(af[ks], bf, acc, 0, 0, 0);
        }
        const int rbase = orow0 + 16 * f + n;
        outT[(d0 + quad * 4 + 0) * NSRC + rbase] = __builtin_amdgcn_exp2f((acc[0] + vb.x) * K2F);
        outT[(d0 + quad * 4 + 1) * NSRC + rbase] = __builtin_amdgcn_exp2f((acc[1] + vb.y) * K2F);
        outT[(d0 + quad * 4 + 2) * NSRC + rbase] = __builtin_amdgcn_exp2f((acc[2] + vb.z) * K2F);
        outT[(d0 + quad * 4 + 3) * NSRC + rbase] = __builtin_amdgcn_exp2f((acc[3] + vb.w) * K2F);
    }
}

// ---------------------------------------------------------------------------
// K3: genp (unchanged from R11) — all-worker, 4-way k-split. Grid (8,8,4),
// 1024 thr = 16 waves = 4/SIMD. Coalesced conflict-free staging -> barrier ->
// barrier-free slice grind (d-pair rcp folding, packed f32x2) -> LDS-tree
// reduction. genP = C0 - 2 * sum_d w_d / (1 + ys*yt),  C0 = sum w + b_res.
// ---------------------------------------------------------------------------
#define GSTR 68
__global__ __launch_bounds__(1024, 4) void genp_kernel(
    const float* __restrict__ yaT, const float* __restrict__ ycT,
    const float* __restrict__ Wres, const float* __restrict__ bres,
    float* __restrict__ out)
{
    __shared__ float lbuf[2 * 64 * GSTR];   // 34.8 KB: ls | lt ; reused for reduce
    float* ls = lbuf;
    float* lt = lbuf + 64 * GSTR;
    __shared__ float c0s;

    const int tid = threadIdx.x;
    const int lane = tid & 63, w = tid >> 6;   // 16 waves
    const int s0 = blockIdx.x * 64;
    const int t0 = blockIdx.y * 64;
    const int b  = blockIdx.z;
    const int sg = b * S_ + s0;
    const int tg = b * T_ + t0;

    if (w == 0) {
        float s = Wres[lane] + Wres[lane + 64] + Wres[lane + 128] + Wres[lane + 192];
        #pragma unroll
        for (int off = 32; off > 0; off >>= 1) s += __shfl_xor(s, off, 64);
        if (lane == 0) c0s = s + bres[0];
    }

    const int q = w >> 2;                       // k-split set 0..3
    const int m = lane & 15;                    // s = s0 + 4m..4m+3
    const int g = (w & 3) * 4 + (lane >> 4);    // t = t0 + 4g..4g+3
    const int dbase = q * 16;                   // set's dloc slice

    f32x2 acc[4][2];                            // [i (t)][jp (s-pair)]
    #pragma unroll
    for (int i = 0; i < 4; i++) {
        acc[i][0] = (f32x2){0.f, 0.f};
        acc[i][1] = (f32x2){0.f, 0.f};
    }

    for (int c = 0; c < 4; c++) {
        __syncthreads();   // previous chunk's readers done
        #pragma unroll
        for (int j = 0; j < 8; j++) {
            int r = w * 8 + j;
            if (r < 64) ls[r * GSTR + lane] = yaT[(c * 64 + r) * NSRC + sg + lane];
            else        lt[(r - 64) * GSTR + lane] = ycT[(c * 64 + r - 64) * NSRC + tg + lane];
        }
        __syncthreads();

        const float* wp = &Wres[c * 64 + dbase];
        const f32x2 one2 = {1.f, 1.f};
        #pragma unroll
        for (int kp = 0; kp < 8; kp++) {
            const int d0 = dbase + 2 * kp, d1 = d0 + 1;
            float4 av0 = *(const float4*)&ls[d0 * GSTR + 4 * m];
            float4 av1 = *(const float4*)&ls[d1 * GSTR + 4 * m];
            float4 cv0 = *(const float4*)&lt[d0 * GSTR + 4 * g];
            float4 cv1 = *(const float4*)&lt[d1 * GSTR + 4 * g];
            const float w0 = wp[2 * kp], w1 = wp[2 * kp + 1];   // uniform s_load
            const f32x2 w0v = {w0, w0}, w1v = {w1, w1};
            f32x2 a0p[2] = {{av0.x, av0.y}, {av0.z, av0.w}};
            f32x2 a1p[2] = {{av1.x, av1.y}, {av1.z, av1.w}};
            const float cc0[4] = {cv0.x, cv0.y, cv0.z, cv0.w};
            const float cc1[4] = {cv1.x, cv1.y, cv1.z, cv1.w};
            #pragma unroll
            for (int i = 0; i < 4; i++) {
                const f32x2 c0v = {cc0[i], cc0[i]};
                const f32x2 c1v = {cc1[i], cc1[i]};
                #pragma unroll
                for (int jp = 0; jp < 2; jp++) {
                    f32x2 dd0 = a0p[jp] * c0v + one2;    // 1 + y0
                    f32x2 dd1 = a1p[jp] * c1v + one2;    // 1 + y1
                    f32x2 den = dd0 * dd1;
                    f32x2 tnu = dd0 * w1v;
                    f32x2 num = dd1 * w0v + tnu;         // w0*dd1 + w1*dd0
                    f32x2 r;
                    r.x = __builtin_amdgcn_rcpf(den.x);
                    r.y = __builtin_amdgcn_rcpf(den.y);
                    acc[i][jp] = num * r + acc[i][jp];
                }
            }
        }
    }

    // ---- reduction of 4 set-partials: q1->q0, q3->q2, then q2->q0 ----
    __syncthreads();
    const int slot = ((w & 3) * 64 + lane) * 17;         // = (g*16+m)*17
    const int slotH = ((q >> 1) * 256 + (w & 3) * 64 + lane) * 17;
    if (q == 1 || q == 3) {
        #pragma unroll
        for (int i = 0; i < 4; i++) {
            float4 p = {acc[i][0].x, acc[i][0].y, acc[i][1].x, acc[i][1].y};
            *(float4*)&lbuf[slotH + 4 * i] = p;
        }
    }
    __syncthreads();
    if (q == 0 || q == 2) {
        #pragma unroll
        for (int i = 0; i < 4; i++) {
            float4 p = *(const float4*)&lbuf[slotH + 4 * i];
            acc[i][0].x += p.x; acc[i][0].y += p.y;
            acc[i][1].x += p.z; acc[i][1].y += p.w;
        }
    }
    __syncthreads();
    if (q == 2) {
        #pragma unroll
        for (int i = 0; i < 4; i++) {
            float4 p = {acc[i][0].x, acc[i][0].y, acc[i][1].x, acc[i][1].y};
            *(float4*)&lbuf[slot + 4 * i] = p;
        }
    }
    __syncthreads();
    if (q == 0) {
        const float C0 = c0s;
        #pragma unroll
        for (int i = 0; i < 4; i++) {
            float4 p = *(const float4*)&lbuf[slot + 4 * i];
            float4 o;
            o.x = C0 - 2.f * (acc[i][0].x + p.x);
            o.y = C0 - 2.f * (acc[i][0].y + p.y);
            o.z = C0 - 2.f * (acc[i][1].x + p.z);
            o.w = C0 - 2.f * (acc[i][1].y + p.w);
            *(float4*)&out[(b * T_ + t0 + 4 * g + i) * S_ + s0 + 4 * m] = o;
        }
    }
}

extern "C" void kernel_launch(void* const* d_in, const int* in_sizes, int n_in,
                              void* d_out, int out_size, void* d_ws, size_t ws_size,
                              hipStream_t stream) {
    const float* source = (const float*)d_in[0];
    const float* target = (const float*)d_in[1];
    const float* W_src  = (const float*)d_in[2];
    const float* b_src  = (const float*)d_in[3];
    const float* W_tgt  = (const float*)d_in[4];
    const float* b_tgt  = (const float*)d_in[5];
    const float* W_res  = (const float*)d_in[6];
    const float* b_res  = (const float*)d_in[7];
    const float* W_prob = (const float*)d_in[8];
    const float* b_prob = (const float*)d_in[9];
    float* out = (float*)d_out;

    unsigned short* abf = (unsigned short*)d_ws;        // 4096*256 bf16 = 2 MB
    unsigned short* wtb = abf + 2 * NSRC * D_;          // 2*256*256 bf16 = 256 KB
    float* yaT = (float*)(wtb + 2 * D_ * D_);           // [256][2048] = 2 MB
    float* ycT = yaT + D_ * NSRC;                       // [256][2048] = 2 MB

    prep_kernel<<<1568, 256, 0, stream>>>(source, target, W_src, W_tgt,
                                          W_prob, b_prob, abf, wtb, out);
    linT_kernel<<<256, 256, 0, stream>>>(abf, wtb, b_src, b_tgt, yaT, ycT);
    genp_kernel<<<dim3(8, 8, 4), 1024, 0, stream>>>(yaT, ycT, W_res, b_res, out);
}

// Round 13
// 107.406 us; speedup vs baseline: 1.1063x; 1.0853x over previous
//
#include <hip/hip_runtime.h>

#define B_ 4
#define S_ 512
#define T_ 512
#define D_ 256
#define NSRC (B_ * S_)            // 2048 source rows
#define K2F 2.8853900817779268f   // 2*log2(e): exp2(x*K2F) = e^(2x)

typedef __attribute__((ext_vector_type(8))) short short8;   // 8 bf16
typedef __attribute__((ext_vector_type(4))) float f32x4;
typedef __attribute__((ext_vector_type(2))) float f32x2;

__device__ __forceinline__ unsigned short f2bf(float f) {
    union { float f; unsigned u; } v; v.f = f;
    unsigned r = v.u + 0x7FFF + ((v.u >> 16) & 1);   // RNE
    return (unsigned short)(r >> 16);
}

// ---------------------------------------------------------------------------
// K1: prep (validated R3). blocks 0..1023: cast [src;tgt] -> abf bf16.
//     blocks 1024..1055: W -> WT bf16 via LDS 64x64 tile transpose.
//     blocks 1056..1567: prob = softmax(target @ W_prob + b_prob).
// ---------------------------------------------------------------------------
__global__ __launch_bounds__(256) void prep_kernel(
    const float* __restrict__ src, const float* __restrict__ tgt,
    const float* __restrict__ Wsrc, const float* __restrict__ Wtgt,
    const float* __restrict__ Wp, const float* __restrict__ bp,
    unsigned short* __restrict__ abf, unsigned short* __restrict__ wtb,
    float* __restrict__ out)
{
    __shared__ float tl[64 * 65];
    const int blk = blockIdx.x, tid = threadIdx.x;

    if (blk < 1024) {
        int i4 = blk * 256 + tid;
        const int half = NSRC * D_ / 4;
        const float4* in = (i4 < half) ? (const float4*)src : (const float4*)tgt;
        int j = (i4 < half) ? i4 : i4 - half;
        float4 v = in[j];
        ushort4 o;
        o.x = f2bf(v.x); o.y = f2bf(v.y); o.z = f2bf(v.z); o.w = f2bf(v.w);
        *(ushort4*)&abf[i4 * 4] = o;
    } else if (blk < 1056) {
        int wb = blk - 1024;
        int e = wb >> 4, ti = wb & 15, tr = ti >> 2, tc = ti & 3;
        int r0 = tr * 64, c0 = tc * 64;
        const float* W = e ? Wtgt : Wsrc;
        #pragma unroll
        for (int it = 0; it < 4; it++) {
            int rr = (tid >> 4) + it * 16;
            int cc = (tid & 15) * 4;
            float4 v = *(const float4*)&W[(r0 + rr) * D_ + c0 + cc];
            tl[(cc + 0) * 65 + rr] = v.x;
            tl[(cc + 1) * 65 + rr] = v.y;
            tl[(cc + 2) * 65 + rr] = v.z;
            tl[(cc + 3) * 65 + rr] = v.w;
        }
        __syncthreads();
        #pragma unroll
        for (int it = 0; it < 2; it++) {
            int jj = (tid >> 3) + it * 32;
            int kk = (tid & 7) * 8;
            ushort4 lo, hi;
            lo.x = f2bf(tl[jj * 65 + kk + 0]); lo.y = f2bf(tl[jj * 65 + kk + 1]);
            lo.z = f2bf(tl[jj * 65 + kk + 2]); lo.w = f2bf(tl[jj * 65 + kk + 3]);
            hi.x = f2bf(tl[jj * 65 + kk + 4]); hi.y = f2bf(tl[jj * 65 + kk + 5]);
            hi.z = f2bf(tl[jj * 65 + kk + 6]); hi.w = f2bf(tl[jj * 65 + kk + 7]);
            int idx = (e * 256 + c0 + jj) * D_ + r0 + kk;
            *(ushort4*)&wtb[idx] = lo;
            *(ushort4*)&wtb[idx + 4] = hi;
        }
    } else {
        int row  = (blk - 1056) * 4 + (tid >> 6);
        int lane = tid & 63;
        float p0 = 0.f, p1 = 0.f;
        #pragma unroll
        for (int i = 0; i < 4; i++) {
            int d = lane + i * 64;
            float v = tgt[row * D_ + d];
            float2 w = *(const float2*)&Wp[d * 2];
            p0 = fmaf(v, w.x, p0);
            p1 = fmaf(v, w.y, p1);
        }
        #pragma unroll
        for (int off = 32; off > 0; off >>= 1) {
            p0 += __shfl_down(p0, off, 64);
            p1 += __shfl_down(p1, off, 64);
        }
        if (lane == 0) {
            const float L2E = 1.4426950408889634f;
            float l0 = p0 + bp[0], l1 = p1 + bp[1];
            float e10 = __builtin_amdgcn_exp2f((l1 - l0) * L2E);
            float e01 = __builtin_amdgcn_exp2f((l0 - l1) * L2E);
            out[B_ * T_ * S_ + row * 2 + 0] = __builtin_amdgcn_rcpf(1.f + e10);
            out[B_ * T_ * S_ + row * 2 + 1] = __builtin_amdgcn_rcpf(1.f + e01);
        }
    }
}

// ---------------------------------------------------------------------------
// K2: mega v9 — R10 structure (best total) + 4-term rcp folding.
// 768 threads = 12 waves = 3/SIMD (1 producer + 2 consumers per SIMD),
// grid (8,8,4) = 256 blocks = 1/CU. Tile 64s x 64t, D in 4 chunks (dbuf LDS).
// Consumers fold FOUR d-terms into one rcp:
//   sum w_i/dd_i = [(w0*dd1+w1*dd0)*dd2*dd3 + (w2*dd3+w3*dd2)*dd0*dd1]
//                  / (dd0*dd1*dd2*dd3)
// halving trans-pipe occupancy vs v8; all full-rate math packed f32x2.
// genP = C0 - 2 * sum_d w_d / (1 + ys*yt),  C0 = sum w + b_res.
// ---------------------------------------------------------------------------
#define LSTR 68
__global__ __launch_bounds__(768, 1) void mega_kernel(
    const unsigned short* __restrict__ abf, const unsigned short* __restrict__ wtb,
    const float* __restrict__ bsrc, const float* __restrict__ btgt,
    const float* __restrict__ Wres, const float* __restrict__ bres,
    float* __restrict__ out)
{
    __shared__ float ls[2][64 * LSTR];   // [buf][d][s]
    __shared__ float lt[2][64 * LSTR];   // [buf][d][t]
    __shared__ float c0s;

    const int tid = threadIdx.x;
    const int lane = tid & 63, w = tid >> 6;
    const int s0 = blockIdx.x * 64;
    const int t0 = blockIdx.y * 64;
    const int b  = blockIdx.z;

    if (w == 0) {
        float s = Wres[lane] + Wres[lane + 64] + Wres[lane + 128] + Wres[lane + 192];
        #pragma unroll
        for (int off = 32; off > 0; off >>= 1) s += __shfl_xor(s, off, 64);
        if (lane == 0) c0s = s + bres[0];
    }

    const bool producer = (w < 4);

    // ---- producer state ----
    const int pw  = w & 3;
    const int mat = pw >> 1;             // 0 = s-mat, 1 = t-mat
    const int rb  = 2 * (pw & 1);        // rowgroup base
    const int n = lane & 15, quad = lane >> 4;
    const float* bias = mat ? btgt : bsrc;
    const unsigned short* wtbase = wtb + mat * 256 * D_;
    const int R0 = mat ? (NSRC + b * T_ + t0) : (b * S_ + s0);

    short8 af[2][8];
    if (producer) {
        #pragma unroll
        for (int rg = 0; rg < 2; rg++)
            #pragma unroll
            for (int ks = 0; ks < 8; ks++)
                af[rg][ks] = *(const short8*)&abf[(R0 + (rb + rg) * 16 + n) * D_ + ks * 32 + quad * 8];
    }

    auto phaseA = [&](int c, int bi) {
        float* lx = (mat ? lt[bi] : ls[bi]);
        #pragma unroll
        for (int cg = 0; cg < 4; cg++) {
            const int gcol = c * 4 + cg;
            const unsigned short* bptr = &wtbase[(gcol * 16 + n) * D_ + quad * 8];
            short8 bf[8];
            #pragma unroll
            for (int ks = 0; ks < 8; ks++) bf[ks] = *(const short8*)&bptr[ks * 32];
            const int dloc = cg * 16 + n;
            const float bv = bias[gcol * 16 + n];
            #pragma unroll
            for (int rg = 0; rg < 2; rg++) {
                f32x4 a4 = {0.f, 0.f, 0.f, 0.f};
                #pragma unroll
                for (int ks = 0; ks < 8; ks++)
                    a4 = __builtin_amdgcn_mfma_f32_16x16x32_bf16(af[rg][ks], bf[ks], a4, 0, 0, 0);
                float4 o;
                o.x = __builtin_amdgcn_exp2f((a4[0] + bv) * K2F);
                o.y = __builtin_amdgcn_exp2f((a4[1] + bv) * K2F);
                o.z = __builtin_amdgcn_exp2f((a4[2] + bv) * K2F);
                o.w = __builtin_amdgcn_exp2f((a4[3] + bv) * K2F);
                *(float4*)&lx[dloc * LSTR + (rb + rg) * 16 + quad * 4] = o;
            }
        }
    };

    // ---- consumer state ----
    const int cl = tid - 256;            // 0..511
    const int m = cl & 15;               // s = s0 + 4m..4m+3
    const int g = cl >> 4;               // t = t0 + 2g, 2g+1   (0..31)
    f32x2 acc[2][2];                     // [t-idx i][s-pair jp]
    #pragma unroll
    for (int i = 0; i < 2; i++) {
        acc[i][0] = (f32x2){0.f, 0.f};
        acc[i][1] = (f32x2){0.f, 0.f};
    }

    if (producer) phaseA(0, 0);
    __syncthreads();

    for (int c = 0; c < 4; c++) {
        const int bi = c & 1;
        if (producer) {
            if (c < 3) phaseA(c + 1, bi ^ 1);
        } else {
            const float* lsb = ls[bi];
            const float* ltb = lt[bi];
            const float* wp = &Wres[c * 64];
            const f32x2 one2 = {1.f, 1.f};
            #pragma unroll 4
            for (int kq = 0; kq < 16; kq++) {
                const int d0 = 4 * kq;
                float4 av0 = *(const float4*)&lsb[(d0 + 0) * LSTR + 4 * m];
                float4 av1 = *(const float4*)&lsb[(d0 + 1) * LSTR + 4 * m];
                float4 av2 = *(const float4*)&lsb[(d0 + 2) * LSTR + 4 * m];
                float4 av3 = *(const float4*)&lsb[(d0 + 3) * LSTR + 4 * m];
                float2 cv0 = *(const float2*)&ltb[(d0 + 0) * LSTR + 2 * g];
                float2 cv1 = *(const float2*)&ltb[(d0 + 1) * LSTR + 2 * g];
                float2 cv2 = *(const float2*)&ltb[(d0 + 2) * LSTR + 2 * g];
                float2 cv3 = *(const float2*)&ltb[(d0 + 3) * LSTR + 2 * g];
                const float w0 = wp[d0], w1 = wp[d0 + 1];   // uniform s_loads
                const float w2 = wp[d0 + 2], w3 = wp[d0 + 3];
                const f32x2 w0v = {w0, w0}, w1v = {w1, w1};
                const f32x2 w2v = {w2, w2}, w3v = {w3, w3};
                f32x2 a0p[2] = {{av0.x, av0.y}, {av0.z, av0.w}};
                f32x2 a1p[2] = {{av1.x, av1.y}, {av1.z, av1.w}};
                f32x2 a2p[2] = {{av2.x, av2.y}, {av2.z, av2.w}};
                f32x2 a3p[2] = {{av3.x, av3.y}, {av3.z, av3.w}};
                const float cc0[2] = {cv0.x, cv0.y};
                const float cc1[2] = {cv1.x, cv1.y};
                const float cc2[2] = {cv2.x, cv2.y};
                const float cc3[2] = {cv3.x, cv3.y};
                #pragma unroll
                for (int i = 0; i < 2; i++) {
                    const f32x2 c0v = {cc0[i], cc0[i]};
                    const f32x2 c1v = {cc1[i], cc1[i]};
                    const f32x2 c2v = {cc2[i], cc2[i]};
                    const f32x2 c3v = {cc3[i], cc3[i]};
                    #pragma unroll
                    for (int jp = 0; jp < 2; jp++) {
                        f32x2 dd0 = a0p[jp] * c0v + one2;    // 1 + y_d
                        f32x2 dd1 = a1p[jp] * c1v + one2;
                        f32x2 dd2 = a2p[jp] * c2v + one2;
                        f32x2 dd3 = a3p[jp] * c3v + one2;
                        f32x2 p01 = dd0 * dd1;
                        f32x2 p23 = dd2 * dd3;
                        f32x2 den = p01 * p23;
                        f32x2 u01 = dd1 * w0v;
                        u01 = dd0 * w1v + u01;               // w0*dd1 + w1*dd0
                        f32x2 u23 = dd3 * w2v;
                        u23 = dd2 * w3v + u23;               // w2*dd3 + w3*dd2
                        f32x2 num = u01 * p23;
                        num = u23 * p01 + num;
                        f32x2 r;
                        r.x = __builtin_amdgcn_rcpf(den.x);
                        r.y = __builtin_amdgcn_rcpf(den.y);
                        acc[i][jp] = num * r + acc[i][jp];
                    }
                }
            }
        }
        __syncthreads();
    }

    if (!producer) {
        const float C0 = c0s;
        #pragma unroll
        for (int i = 0; i < 2; i++) {
            float4 o;
            o.x = C0 - 2.f * acc[i][0].x;
            o.y = C0 - 2.f * acc[i][0].y;
            o.z = C0 - 2.f * acc[i][1].x;
            o.w = C0 - 2.f * acc[i][1].y;
            *(float4*)&out[(b * T_ + t0 + 2 * g + i) * S_ + s0 + 4 * m] = o;
        }
    }
}

extern "C" void kernel_launch(void* const* d_in, const int* in_sizes, int n_in,
                              void* d_out, int out_size, void* d_ws, size_t ws_size,
                              hipStream_t stream) {
    const float* source = (const float*)d_in[0];
    const float* target = (const float*)d_in[1];
    const float* W_src  = (const float*)d_in[2];
    const float* b_src  = (const float*)d_in[3];
    const float* W_tgt  = (const float*)d_in[4];
    const float* b_tgt  = (const float*)d_in[5];
    const float* W_res  = (const float*)d_in[6];
    const float* b_res  = (const float*)d_in[7];
    const float* W_prob = (const float*)d_in[8];
    const float* b_prob = (const float*)d_in[9];
    float* out = (float*)d_out;

    unsigned short* abf = (unsigned short*)d_ws;        // 4096*256 bf16 = 2 MB
    unsigned short* wtb = abf + 2 * NSRC * D_;          // 2*256*256 bf16 = 256 KB

    prep_kernel<<<1568, 256, 0, stream>>>(source, target, W_src, W_tgt,
                                          W_prob, b_prob, abf, wtb, out);
    mega_kernel<<<dim3(8, 8, 4), 768, 0, stream>>>(abf, wtb, b_src, b_tgt,
                                                   W_res, b_res, out);
}